// Round 12
// baseline (975.156 us; speedup 1.0000x reference)
//
#include <hip/hip_runtime.h>
#include <cstdint>
#include <cstddef>

// ---------------- problem constants ----------------
#define VOCAB 32000
#define EMB   256
#define HID   1024
#define NB    16      // batch
#define SS    512     // seq
#define MTOK  (NB*SS) // 8192 tokens
#define KDIM  1024    // NM1*EMB = HID
#define NCHUNK 500    // 32000 / 64 cols per chunk
#define PSTRIDE 512   // padded chunk stride

typedef __bf16 bf16_t;
typedef bf16_t bf16x8 __attribute__((ext_vector_type(8)));
typedef float  f32x4  __attribute__((ext_vector_type(4)));
typedef float  f32x16 __attribute__((ext_vector_type(16)));
typedef int    i32x4  __attribute__((ext_vector_type(4)));
typedef int    i32x8  __attribute__((ext_vector_type(8)));

__device__ __forceinline__ unsigned short f32_to_bf16(float f) {
  union { float f; unsigned int u; } v; v.f = f;
  unsigned int u = v.u;
  unsigned int r = (u + 0x7FFFu + ((u >> 16) & 1u)) >> 16; // RNE
  return (unsigned short)r;
}

// f32 -> OCP e4m3fn, RNE, software (input assumed |x| <= 448)
__device__ __forceinline__ uint8_t f32_to_e4m3(float x) {
  union { float f; uint32_t u; } v; v.f = x;
  uint32_t s = (v.u >> 24) & 0x80u;
  int e = (int)((v.u >> 23) & 0xffu) - 127;
  uint32_t m = v.u & 0x7fffffu;
  if (e < -9) return (uint8_t)s;                  // -> 0
  if (e >= -6) {                                  // normal range
    uint32_t keep = m >> 20;
    uint32_t rest = m & 0xfffffu;
    keep += (rest > 0x80000u) || (rest == 0x80000u && (keep & 1u));
    if (keep == 8u) { keep = 0u; e += 1; }
    int code = ((e + 7) << 3) | (int)keep;
    if (code >= 0x7f) code = 0x7e;                // clamp to 448 (avoid NaN)
    return (uint8_t)(s | (uint32_t)code);
  }
  // subnormal
  uint32_t full = 0x800000u | m;
  int shift = 20 + (-6 - e);                      // 21..23
  uint32_t keep = full >> shift;
  uint32_t rest = full & ((1u << shift) - 1u);
  uint32_t half = 1u << (shift - 1);
  keep += (rest > half) || (rest == half && (keep & 1u));
  if (keep >= 8u) return (uint8_t)(s | 0x08u);
  return (uint8_t)(s | keep);
}

__device__ __forceinline__ void gload_lds16(const void* gsrc, void* ldst) {
  __builtin_amdgcn_global_load_lds(
      (__attribute__((address_space(1))) void*)gsrc,
      (__attribute__((address_space(3))) void*)ldst,
      16, 0, 0);
}

#define MEMFENCE asm volatile("" ::: "memory")

// ---------------- transpose + convert: in[R][C] f32 -> out[C][R] ----------------
__global__ void k_transpose_bf16(const float* __restrict__ in,
                                 unsigned short* __restrict__ out,
                                 int R, int C) {
  __shared__ float tile[32][33];
  int bc = blockIdx.x * 32, br = blockIdx.y * 32;
  int tx = threadIdx.x & 31, ty = threadIdx.x >> 5;
#pragma unroll
  for (int i = 0; i < 32; i += 8)
    tile[ty + i][tx] = in[(size_t)(br + ty + i) * C + (bc + tx)];
  __syncthreads();
#pragma unroll
  for (int i = 0; i < 32; i += 8)
    out[(size_t)(bc + ty + i) * R + (br + tx)] = f32_to_bf16(tile[tx][ty + i]);
}

__global__ void k_transpose_fp8(const float* __restrict__ in,
                                uint8_t* __restrict__ out,
                                int R, int C) {
  __shared__ float tile[32][33];
  int bc = blockIdx.x * 32, br = blockIdx.y * 32;
  int tx = threadIdx.x & 31, ty = threadIdx.x >> 5;
#pragma unroll
  for (int i = 0; i < 32; i += 8)
    tile[ty + i][tx] = in[(size_t)(br + ty + i) * C + (bc + tx)];
  __syncthreads();
#pragma unroll
  for (int i = 0; i < 32; i += 8)
    out[(size_t)(bc + ty + i) * R + (br + tx)] = f32_to_e4m3(tile[tx][ty + i] * 16.0f);
}

// ---------------- embedding gather ----------------
__global__ void k_gather_e(const int* __restrict__ text,
                           const float* __restrict__ embed,
                           unsigned short* __restrict__ E) {
  int t = blockIdx.x;
  int b = t >> 9, s = t & 511;
  int d = threadIdx.x; // 0..255
#pragma unroll
  for (int j = 0; j < 4; ++j) {
    int sidx = s + j - 4;
    int tok = (sidx >= 0) ? text[b * SS + sidx] : 0;
    float val = (tok != 0) ? embed[(size_t)tok * EMB + d] : 0.0f;
    E[(size_t)t * KDIM + j * EMB + d] = f32_to_bf16(val);
  }
}

// ---------------- FFN GEMM (128x128 tile, relu+bias; OUTQ=1 -> fp8 x16) ----------------
template<int OUTQ>
__global__ __launch_bounds__(256)
void k_gemm_ffn(const unsigned short* __restrict__ A,
                const unsigned short* __restrict__ Bt,
                const float* __restrict__ bias,
                void* __restrict__ Hout, int N) {
  __shared__ unsigned short As[128 * 32];
  __shared__ unsigned short Bs[128 * 32];
  const int tid  = threadIdx.x;
  const int bn   = blockIdx.x, bm = blockIdx.y;
  const int lane = tid & 63, wid = tid >> 6;
  const int wm = wid >> 1, wn = wid & 1;
  const int g = lane >> 4, c = lane & 15;

  f32x4 acc[4][4];
#pragma unroll
  for (int m = 0; m < 4; ++m)
#pragma unroll
    for (int n = 0; n < 4; ++n) { f32x4 z = {0.f, 0.f, 0.f, 0.f}; acc[m][n] = z; }

  const int arow = tid >> 2;
  const int slotb = ((tid & 3) ^ ((tid >> 3) & 3)) * 16;
  const char* gA0 = (const char*)A + ((size_t)(bm * 128 + arow) * KDIM) * 2 + slotb;
  const char* gA1 = gA0 + (size_t)64 * KDIM * 2;
  const char* gB0 = (const char*)Bt + ((size_t)(bn * 128 + arow) * KDIM) * 2 + slotb;
  const char* gB1 = gB0 + (size_t)64 * KDIM * 2;
  char* lA = (char*)As + tid * 16;
  char* lB = (char*)Bs + tid * 16;

  const int rs = (g ^ ((c >> 1) & 3)) * 8;

  for (int kt = 0; kt < KDIM / 32; ++kt) {
    const int kb = kt * 64;
    gload_lds16(gA0 + kb, lA);
    gload_lds16(gA1 + kb, lA + 4096);
    gload_lds16(gB0 + kb, lB);
    gload_lds16(gB1 + kb, lB + 4096);
    __syncthreads();

    bf16x8 af[4], bf[4];
#pragma unroll
    for (int m = 0; m < 4; ++m)
      af[m] = *(const bf16x8*)&As[(wm * 64 + m * 16 + c) * 32 + rs];
#pragma unroll
    for (int n = 0; n < 4; ++n)
      bf[n] = *(const bf16x8*)&Bs[(wn * 64 + n * 16 + c) * 32 + rs];
#pragma unroll
    for (int m = 0; m < 4; ++m)
#pragma unroll
      for (int n = 0; n < 4; ++n)
        acc[m][n] = __builtin_amdgcn_mfma_f32_16x16x32_bf16(af[m], bf[n], acc[m][n], 0, 0, 0);
    __syncthreads();
  }

#pragma unroll
  for (int n = 0; n < 4; ++n) {
    int colg = bn * 128 + wn * 64 + n * 16 + c;
    float bv = bias[colg];
#pragma unroll
    for (int m = 0; m < 4; ++m)
#pragma unroll
      for (int j = 0; j < 4; ++j) {
        int rowg = bm * 128 + wm * 64 + m * 16 + g * 4 + j;
        float v = acc[m][n][j] + bv;
        v = v > 0.f ? v : 0.f;
        if constexpr (OUTQ == 0)
          ((unsigned short*)Hout)[(size_t)rowg * N + colg] = f32_to_bf16(v);
        else
          ((uint8_t*)Hout)[(size_t)rowg * N + colg] = f32_to_e4m3(v * 16.0f);
      }
  }
}

// ---------------- vocab GEMM: MX-fp8, 256x128 block, BK=64, 8 waves, 3-buf pipeline ----
// A/B pre-scaled by 2^4; MFMA scale operands 2^-4 (e8m0 byte 123).
// R12 = R11 (geometry/regs/swizzle proven) + T4 counted-vmcnt pipeline:
// triple-buffered LDS (72 KB, 2 blocks/CU), stage tile T+2 at body T, gate with
// s_waitcnt vmcnt(6) (T's loads landed; T+1/T+2's 6 stay IN FLIGHT across the raw
// s_barrier -- never drain in the loop; m218: counted-vs-drain0 = +38-73%).
// Hazard: STAGE(T+2) overwrites buf[(T-1)%3]; readers of T-1 passed the previous
// exit barrier. Entry barrier after vmcnt makes all waves' T-loads visible.
__global__ __launch_bounds__(512, 2)
void k_gemm_vocab_mx(const uint8_t* __restrict__ Aq,   // [MTOK][KDIM] fp8 (x16)
                     const uint8_t* __restrict__ Bq,   // [VOCAB][KDIM] fp8 (x16)
                     const float* __restrict__ bias,
                     float* __restrict__ pmax, float* __restrict__ psum,
                     float* __restrict__ tlog, const int* __restrict__ target) {
  __shared__ uint8_t As[3][256 * 64];  // 48 KB
  __shared__ uint8_t Bs[3][128 * 64];  // 24 KB
  const int tid  = threadIdx.x;
  const int lane = tid & 63, wid = tid >> 6;   // 8 waves
  const int wm = wid >> 1, wn = wid & 1;       // 4(M) x 2(N); per-wave out 64x64
  const int lr = lane & 31, kb = lane >> 5;
  const int kb2 = kb << 1;

  // bijective XCD-chunked swizzle; grid = 8000 = 32(bm) x 250(bn)
  const int o   = blockIdx.x;
  const int xcd = o & 7, idx = o >> 3;         // idx 0..999
  const int bm  = xcd * 4 + (idx & 3);         // 0..31
  const int bn  = idx >> 2;                    // 0..249

  f32x16 acc[2][2];
#pragma unroll
  for (int m = 0; m < 2; ++m)
#pragma unroll
    for (int n = 0; n < 2; ++n)
#pragma unroll
      for (int e = 0; e < 16; ++e) acc[m][n][e] = 0.f;

  // staging: thread t -> row (t>>2) (+128 for A's 2nd issue), LDS quad t&3;
  // source quad (t&3)^((row>>1)&3); invariant under row += 128.
  const int srow = tid >> 2, sq = tid & 3;     // srow 0..127 (512 threads)
  const int gq = sq ^ ((srow >> 1) & 3);
  const uint8_t* pA = Aq + (size_t)bm * 256 * KDIM + (size_t)srow * KDIM + gq * 16;
  const uint8_t* pB = Bq + (size_t)bn * 128 * KDIM + (size_t)srow * KDIM + gq * 16;
  uint8_t* const lA0 = &As[0][0] + tid * 16;   // per-buffer A stride 16384 B
  uint8_t* const lA1 = &As[1][0] + tid * 16;
  uint8_t* const lA2 = &As[2][0] + tid * 16;
  uint8_t* const lB0 = &Bs[0][0] + tid * 16;   // per-buffer B stride 8192 B
  uint8_t* const lB1 = &Bs[1][0] + tid * 16;
  uint8_t* const lB2 = &Bs[2][0] + tid * 16;

  // A: 256 rows = 2 issues (128*KDIM = 131072 B apart); B: 128 rows = 1 issue.
#define STAGE(kt_, la_, lb_) do {                                          \
    const size_t ko_ = (size_t)(kt_) * 64;                                 \
    gload_lds16(pA + ko_,          la_);                                   \
    gload_lds16(pA + ko_ + 131072, la_ + 8192);                            \
    gload_lds16(pB + ko_,          lb_);                                   \
  } while (0)

  // hoisted read addressing: row bases (buf0) + swizzled quad byte offsets
  const int swz = (lr >> 1) & 3;
  const int q0 = ((kb2 | 0) ^ swz) * 16;
  const int q1 = ((kb2 | 1) ^ swz) * 16;
  const uint8_t* const aR0 = &As[0][(wm * 64 +      lr) * 64];
  const uint8_t* const aR1 = &As[0][(wm * 64 + 32 + lr) * 64];
  const uint8_t* const bR0 = &Bs[0][(wn * 64 +      lr) * 64];
  const uint8_t* const bR1 = &Bs[0][(wn * 64 + 32 + lr) * 64];

#define RD(dst_, base_, bofs_) do {                                        \
    i32x4 lo_ = *(const i32x4*)((base_) + (bofs_) + q0);                   \
    i32x4 hi_ = *(const i32x4*)((base_) + (bofs_) + q1);                   \
    dst_ = __builtin_shufflevector(lo_, hi_, 0, 1, 2, 3, 4, 5, 6, 7);      \
  } while (0)

#define VMW6 asm volatile("s_waitcnt vmcnt(6)" ::: "memory")
#define VMW3 asm volatile("s_waitcnt vmcnt(3)" ::: "memory")
#define VMW0 asm volatile("s_waitcnt vmcnt(0)" ::: "memory")

  // BODY consumes buf B_ (K-tile T_); stages tile T_+2 into buf (B_+2)%3 first.
  // VMW_: counted gate = 3 * (tiles staged beyond T_).
#define BODY(B_, T_, DOSTAGE_, laS_, lbS_, VMW_) do {                      \
    if (DOSTAGE_) STAGE((T_) + 2, laS_, lbS_);                             \
    VMW_;                                                                  \
    __builtin_amdgcn_s_barrier();                                          \
    MEMFENCE;                                                              \
    i32x8 b0, b1, a0, a1;                                                  \
    RD(b0, bR0, (B_) * 8192);                                              \
    RD(b1, bR1, (B_) * 8192);                                              \
    RD(a0, aR0, (B_) * 16384);                                             \
    RD(a1, aR1, (B_) * 16384);                                             \
    __builtin_amdgcn_s_setprio(1);                                         \
    acc[0][0] = __builtin_amdgcn_mfma_scale_f32_32x32x64_f8f6f4(           \
        a0, b0, acc[0][0], 0, 0, 0, 123, 0, 123);                          \
    acc[0][1] = __builtin_amdgcn_mfma_scale_f32_32x32x64_f8f6f4(           \
        a0, b1, acc[0][1], 0, 0, 0, 123, 0, 123);                          \
    acc[1][0] = __builtin_amdgcn_mfma_scale_f32_32x32x64_f8f6f4(           \
        a1, b0, acc[1][0], 0, 0, 0, 123, 0, 123);                          \
    acc[1][1] = __builtin_amdgcn_mfma_scale_f32_32x32x64_f8f6f4(           \
        a1, b1, acc[1][1], 0, 0, 0, 123, 0, 123);                          \
    __builtin_amdgcn_s_setprio(0);                                         \
    MEMFENCE;                                                              \
    __builtin_amdgcn_s_barrier();                                          \
    MEMFENCE;                                                              \
  } while (0)

  STAGE(0, lA0, lB0);
  STAGE(1, lA1, lB1);

#pragma unroll 1
  for (int k5 = 0; k5 < 4; ++k5) {   // T = 0..11
    BODY(0, 3 * k5,     true, lA2, lB2, VMW6);
    BODY(1, 3 * k5 + 1, true, lA0, lB0, VMW6);
    BODY(2, 3 * k5 + 2, true, lA1, lB1, VMW6);
  }
  BODY(0, 12, true,  lA2, lB2, VMW6);
  BODY(1, 13, true,  lA0, lB0, VMW6);
  BODY(2, 14, false, lA1, lB1, VMW3);
  BODY(0, 15, false, lA1, lB1, VMW0);
#undef STAGE
#undef RD
#undef BODY
#undef VMW6
#undef VMW3
#undef VMW0

  // ---- epilogue: fused softmax stats per 64-col wave chunk ----
  // C/D 32x32 layout: col = lane&31, row = (reg&3) + 8*(reg>>2) + 4*(lane>>5)
  const int chunk = bn * 2 + wn;
  const int colbase = bn * 128 + wn * 64;
  float bov0 = bias[colbase + lr];
  float bov1 = bias[colbase + 32 + lr];
#pragma unroll
  for (int m = 0; m < 2; ++m) {
#pragma unroll
    for (int reg = 0; reg < 16; ++reg) {
      int rowg = bm * 256 + wm * 64 + m * 32 + (reg & 3) + 8 * (reg >> 2) + 4 * kb;
      float v0 = acc[m][0][reg] + bov0;
      float v1 = acc[m][1][reg] + bov1;
      float mv = fmaxf(v0, v1);
#pragma unroll
      for (int sft = 1; sft < 32; sft <<= 1) mv = fmaxf(mv, __shfl_xor(mv, sft));
      float se = __expf(v0 - mv) + __expf(v1 - mv);
#pragma unroll
      for (int sft = 1; sft < 32; sft <<= 1) se += __shfl_xor(se, sft);
      if (lr == 0) {
        pmax[(size_t)rowg * PSTRIDE + chunk] = mv;
        psum[(size_t)rowg * PSTRIDE + chunk] = se;
      }
      int cw = target[rowg] - colbase;
      if (cw >= 0 && cw < 64 && lr == (cw & 31)) {
        tlog[rowg] = (cw < 32) ? v0 : v1;
      }
    }
  }
}

// ---------------- combine per-chunk stats -> nll per row ----------------
__global__ void k_reduce_nll(const float* __restrict__ pmax,
                             const float* __restrict__ psum,
                             const float* __restrict__ tlog,
                             float* __restrict__ nll) {
  int row = blockIdx.x;
  int lane = threadIdx.x; // 64
  float M = -1e30f;
  for (int ch = lane; ch < NCHUNK; ch += 64) M = fmaxf(M, pmax[(size_t)row * PSTRIDE + ch]);
#pragma unroll
  for (int s = 1; s < 64; s <<= 1) M = fmaxf(M, __shfl_xor(M, s));
  float L = 0.f;
  for (int ch = lane; ch < NCHUNK; ch += 64)
    L += __expf(pmax[(size_t)row * PSTRIDE + ch] - M) * psum[(size_t)row * PSTRIDE + ch];
#pragma unroll
  for (int s = 1; s < 64; s <<= 1) L += __shfl_xor(L, s);
  if (lane == 0) nll[row] = -(tlog[row] - M - logf(L));
}

// ---------------- masked per-step mean -> scalar loss ----------------
__global__ void k_loss(const int* __restrict__ target,
                       const float* __restrict__ nll,
                       float* __restrict__ out) {
  __shared__ float red[SS];
  int s = threadIdx.x; // 512
  float sl = 0.f, cnt = 0.f;
#pragma unroll
  for (int b = 0; b < NB; ++b) {
    int idx = b * SS + s;
    if (target[idx] != 0) { sl += nll[idx]; cnt += 1.f; }
  }
  red[s] = sl / fmaxf(cnt, 1.f);
  __syncthreads();
  for (int st = 256; st > 0; st >>= 1) {
    if (s < st) red[s] += red[s + st];
    __syncthreads();
  }
  if (s == 0) out[0] = red[0] / (float)SS;
}

// ---------------- launch ----------------
extern "C" void kernel_launch(void* const* d_in, const int* in_sizes, int n_in,
                              void* d_out, int out_size, void* d_ws, size_t ws_size,
                              hipStream_t stream) {
  (void)in_sizes; (void)n_in; (void)out_size; (void)ws_size;
  const int*   text   = (const int*)d_in[0];
  const int*   target = (const int*)d_in[1];
  const float* embed  = (const float*)d_in[2];
  const float* W1     = (const float*)d_in[3];
  const float* b1     = (const float*)d_in[4];
  const float* W2     = (const float*)d_in[5];
  const float* b2     = (const float*)d_in[6];
  const float* Wo     = (const float*)d_in[7];
  const float* bo     = (const float*)d_in[8];
  float* out = (float*)d_out;
  char* ws = (char*)d_ws;

  const size_t SZ_E = (size_t)MTOK * KDIM * 2;          // 16.78 MB (bf16)
  unsigned short* E   = (unsigned short*)(ws);
  unsigned short* H1  = (unsigned short*)(ws + SZ_E);
  uint8_t*        H2Q = (uint8_t*)(ws + 2 * SZ_E);      // fp8, 8.39 MB
  char* p = ws + 2 * SZ_E + (size_t)MTOK * KDIM;
  unsigned short* W1t = (unsigned short*)p;  p += (size_t)HID * HID * 2;
  unsigned short* W2t = (unsigned short*)p;  p += (size_t)HID * HID * 2;
  uint8_t*        WoQ = (uint8_t*)p;         p += (size_t)VOCAB * HID;   // fp8, 32.77 MB
  float* tlog = (float*)p;                   p += (size_t)MTOK * 4;
  float* nll  = (float*)p;
  float* pmax = (float*)E;   // E dead after GEMM1
  float* psum = (float*)H1;  // H1 dead after GEMM2

  k_transpose_bf16<<<dim3(HID / 32, HID / 32), 256, 0, stream>>>(W1, W1t, HID, HID);
  k_transpose_bf16<<<dim3(HID / 32, HID / 32), 256, 0, stream>>>(W2, W2t, HID, HID);
  k_transpose_fp8 <<<dim3(VOCAB / 32, HID / 32), 256, 0, stream>>>(Wo, WoQ, HID, VOCAB);
  k_gather_e<<<MTOK, 256, 0, stream>>>(text, embed, E);

  k_gemm_ffn<0><<<dim3(HID / 128, MTOK / 128), 256, 0, stream>>>(E, W1t, b1, (void*)H1, HID);
  k_gemm_ffn<1><<<dim3(HID / 128, MTOK / 128), 256, 0, stream>>>(H1, W2t, b2, (void*)H2Q, HID);

  k_gemm_vocab_mx<<<dim3((MTOK / 256) * (VOCAB / 128)), 512, 0, stream>>>(
      H2Q, WoQ, bo, pmax, psum, tlog, target);

  k_reduce_nll<<<MTOK, 64, 0, stream>>>(pmax, psum, tlog, nll);
  k_loss<<<1, SS, 0, stream>>>(target, nll, out);
}

// Round 13
// 641.673 us; speedup vs baseline: 1.5197x; 1.5197x over previous
//
#include <hip/hip_runtime.h>
#include <cstdint>
#include <cstddef>

// ---------------- problem constants ----------------
#define VOCAB 32000
#define EMB   256
#define HID   1024
#define NB    16      // batch
#define SS    512     // seq
#define MTOK  (NB*SS) // 8192 tokens
#define KDIM  1024    // NM1*EMB = HID
#define NCHUNK 500    // 32000 / 64 cols per chunk
#define PSTRIDE 512   // padded chunk stride

typedef __bf16 bf16_t;
typedef bf16_t bf16x8 __attribute__((ext_vector_type(8)));
typedef float  f32x4  __attribute__((ext_vector_type(4)));
typedef float  f32x16 __attribute__((ext_vector_type(16)));
typedef int    i32x4  __attribute__((ext_vector_type(4)));
typedef int    i32x8  __attribute__((ext_vector_type(8)));

__device__ __forceinline__ unsigned short f32_to_bf16(float f) {
  union { float f; unsigned int u; } v; v.f = f;
  unsigned int u = v.u;
  unsigned int r = (u + 0x7FFFu + ((u >> 16) & 1u)) >> 16; // RNE
  return (unsigned short)r;
}

// f32 -> OCP e4m3fn, RNE, software (input assumed |x| <= 448)
__device__ __forceinline__ uint8_t f32_to_e4m3(float x) {
  union { float f; uint32_t u; } v; v.f = x;
  uint32_t s = (v.u >> 24) & 0x80u;
  int e = (int)((v.u >> 23) & 0xffu) - 127;
  uint32_t m = v.u & 0x7fffffu;
  if (e < -9) return (uint8_t)s;                  // -> 0
  if (e >= -6) {                                  // normal range
    uint32_t keep = m >> 20;
    uint32_t rest = m & 0xfffffu;
    keep += (rest > 0x80000u) || (rest == 0x80000u && (keep & 1u));
    if (keep == 8u) { keep = 0u; e += 1; }
    int code = ((e + 7) << 3) | (int)keep;
    if (code >= 0x7f) code = 0x7e;                // clamp to 448 (avoid NaN)
    return (uint8_t)(s | (uint32_t)code);
  }
  // subnormal
  uint32_t full = 0x800000u | m;
  int shift = 20 + (-6 - e);                      // 21..23
  uint32_t keep = full >> shift;
  uint32_t rest = full & ((1u << shift) - 1u);
  uint32_t half = 1u << (shift - 1);
  keep += (rest > half) || (rest == half && (keep & 1u));
  if (keep >= 8u) return (uint8_t)(s | 0x08u);
  return (uint8_t)(s | keep);
}

__device__ __forceinline__ void gload_lds16(const void* gsrc, void* ldst) {
  __builtin_amdgcn_global_load_lds(
      (__attribute__((address_space(1))) void*)gsrc,
      (__attribute__((address_space(3))) void*)ldst,
      16, 0, 0);
}

#define MEMFENCE asm volatile("" ::: "memory")

// ---------------- transpose + convert: in[R][C] f32 -> out[C][R] ----------------
__global__ void k_transpose_bf16(const float* __restrict__ in,
                                 unsigned short* __restrict__ out,
                                 int R, int C) {
  __shared__ float tile[32][33];
  int bc = blockIdx.x * 32, br = blockIdx.y * 32;
  int tx = threadIdx.x & 31, ty = threadIdx.x >> 5;
#pragma unroll
  for (int i = 0; i < 32; i += 8)
    tile[ty + i][tx] = in[(size_t)(br + ty + i) * C + (bc + tx)];
  __syncthreads();
#pragma unroll
  for (int i = 0; i < 32; i += 8)
    out[(size_t)(bc + ty + i) * R + (br + tx)] = f32_to_bf16(tile[tx][ty + i]);
}

__global__ void k_transpose_fp8(const float* __restrict__ in,
                                uint8_t* __restrict__ out,
                                int R, int C) {
  __shared__ float tile[32][33];
  int bc = blockIdx.x * 32, br = blockIdx.y * 32;
  int tx = threadIdx.x & 31, ty = threadIdx.x >> 5;
#pragma unroll
  for (int i = 0; i < 32; i += 8)
    tile[ty + i][tx] = in[(size_t)(br + ty + i) * C + (bc + tx)];
  __syncthreads();
#pragma unroll
  for (int i = 0; i < 32; i += 8)
    out[(size_t)(bc + ty + i) * R + (br + tx)] = f32_to_e4m3(tile[tx][ty + i] * 16.0f);
}

// ---------------- embedding gather ----------------
__global__ void k_gather_e(const int* __restrict__ text,
                           const float* __restrict__ embed,
                           unsigned short* __restrict__ E) {
  int t = blockIdx.x;
  int b = t >> 9, s = t & 511;
  int d = threadIdx.x; // 0..255
#pragma unroll
  for (int j = 0; j < 4; ++j) {
    int sidx = s + j - 4;
    int tok = (sidx >= 0) ? text[b * SS + sidx] : 0;
    float val = (tok != 0) ? embed[(size_t)tok * EMB + d] : 0.0f;
    E[(size_t)t * KDIM + j * EMB + d] = f32_to_bf16(val);
  }
}

// ---------------- FFN GEMM (128x128 tile, relu+bias; OUTQ=1 -> fp8 x16) ----------------
template<int OUTQ>
__global__ __launch_bounds__(256)
void k_gemm_ffn(const unsigned short* __restrict__ A,
                const unsigned short* __restrict__ Bt,
                const float* __restrict__ bias,
                void* __restrict__ Hout, int N) {
  __shared__ unsigned short As[128 * 32];
  __shared__ unsigned short Bs[128 * 32];
  const int tid  = threadIdx.x;
  const int bn   = blockIdx.x, bm = blockIdx.y;
  const int lane = tid & 63, wid = tid >> 6;
  const int wm = wid >> 1, wn = wid & 1;
  const int g = lane >> 4, c = lane & 15;

  f32x4 acc[4][4];
#pragma unroll
  for (int m = 0; m < 4; ++m)
#pragma unroll
    for (int n = 0; n < 4; ++n) { f32x4 z = {0.f, 0.f, 0.f, 0.f}; acc[m][n] = z; }

  const int arow = tid >> 2;
  const int slotb = ((tid & 3) ^ ((tid >> 3) & 3)) * 16;
  const char* gA0 = (const char*)A + ((size_t)(bm * 128 + arow) * KDIM) * 2 + slotb;
  const char* gA1 = gA0 + (size_t)64 * KDIM * 2;
  const char* gB0 = (const char*)Bt + ((size_t)(bn * 128 + arow) * KDIM) * 2 + slotb;
  const char* gB1 = gB0 + (size_t)64 * KDIM * 2;
  char* lA = (char*)As + tid * 16;
  char* lB = (char*)Bs + tid * 16;

  const int rs = (g ^ ((c >> 1) & 3)) * 8;

  for (int kt = 0; kt < KDIM / 32; ++kt) {
    const int kb = kt * 64;
    gload_lds16(gA0 + kb, lA);
    gload_lds16(gA1 + kb, lA + 4096);
    gload_lds16(gB0 + kb, lB);
    gload_lds16(gB1 + kb, lB + 4096);
    __syncthreads();

    bf16x8 af[4], bf[4];
#pragma unroll
    for (int m = 0; m < 4; ++m)
      af[m] = *(const bf16x8*)&As[(wm * 64 + m * 16 + c) * 32 + rs];
#pragma unroll
    for (int n = 0; n < 4; ++n)
      bf[n] = *(const bf16x8*)&Bs[(wn * 64 + n * 16 + c) * 32 + rs];
#pragma unroll
    for (int m = 0; m < 4; ++m)
#pragma unroll
      for (int n = 0; n < 4; ++n)
        acc[m][n] = __builtin_amdgcn_mfma_f32_16x16x32_bf16(af[m], bf[n], acc[m][n], 0, 0, 0);
    __syncthreads();
  }

#pragma unroll
  for (int n = 0; n < 4; ++n) {
    int colg = bn * 128 + wn * 64 + n * 16 + c;
    float bv = bias[colg];
#pragma unroll
    for (int m = 0; m < 4; ++m)
#pragma unroll
      for (int j = 0; j < 4; ++j) {
        int rowg = bm * 128 + wm * 64 + m * 16 + g * 4 + j;
        float v = acc[m][n][j] + bv;
        v = v > 0.f ? v : 0.f;
        if constexpr (OUTQ == 0)
          ((unsigned short*)Hout)[(size_t)rowg * N + colg] = f32_to_bf16(v);
        else
          ((uint8_t*)Hout)[(size_t)rowg * N + colg] = f32_to_e4m3(v * 16.0f);
      }
  }
}

// ---------------- vocab GEMM: MX-fp8, 256x128 block, BK=64, 8 waves, counted vmcnt ----
// A/B pre-scaled by 2^4; MFMA scale operands 2^-4 (e8m0 byte 123).
// R13 = R11 exactly (48KB dbuf -> ~2 blocks/CU; 64 VGPR + 64 AGPR) with ONE change:
// the per-tile __syncthreads() (which drains vmcnt to 0, exposing the just-issued
// prefetch) is replaced by counted s_waitcnt vmcnt(3) + raw s_barrier. The gate
// waits only tile T's 3 loads (issued one body ago); tile T+1's 3 loads stay in
// flight across both barriers (T4, m218). R12's 3-buf variant lost 2-blocks/CU to
// the >64KB LDS cliff (72KB -> 1 block/CU, measured) -- dbuf avoids that.
// Hazards: STAGE(T+1) overwrites buf^1 only after body T-1's exit barrier (readers
// done); entry barrier after per-wave vmcnt makes all waves' tile-T writes visible.
__global__ __launch_bounds__(512, 2)
void k_gemm_vocab_mx(const uint8_t* __restrict__ Aq,   // [MTOK][KDIM] fp8 (x16)
                     const uint8_t* __restrict__ Bq,   // [VOCAB][KDIM] fp8 (x16)
                     const float* __restrict__ bias,
                     float* __restrict__ pmax, float* __restrict__ psum,
                     float* __restrict__ tlog, const int* __restrict__ target) {
  __shared__ uint8_t As[2][256 * 64];  // 32 KB
  __shared__ uint8_t Bs[2][128 * 64];  // 16 KB
  const int tid  = threadIdx.x;
  const int lane = tid & 63, wid = tid >> 6;   // 8 waves
  const int wm = wid >> 1, wn = wid & 1;       // 4(M) x 2(N); per-wave out 64x64
  const int lr = lane & 31, kb = lane >> 5;
  const int kb2 = kb << 1;

  // bijective XCD-chunked swizzle; grid = 8000 = 32(bm) x 250(bn)
  const int o   = blockIdx.x;
  const int xcd = o & 7, idx = o >> 3;         // idx 0..999
  const int bm  = xcd * 4 + (idx & 3);         // 0..31
  const int bn  = idx >> 2;                    // 0..249

  f32x16 acc[2][2];
#pragma unroll
  for (int m = 0; m < 2; ++m)
#pragma unroll
    for (int n = 0; n < 2; ++n)
#pragma unroll
      for (int e = 0; e < 16; ++e) acc[m][n][e] = 0.f;

  // staging: thread t -> row (t>>2) (+128 for A's 2nd issue), LDS quad t&3;
  // source quad (t&3)^((row>>1)&3); invariant under row += 128.
  const int srow = tid >> 2, sq = tid & 3;     // srow 0..127 (512 threads)
  const int gq = sq ^ ((srow >> 1) & 3);
  const uint8_t* pA = Aq + (size_t)bm * 256 * KDIM + (size_t)srow * KDIM + gq * 16;
  const uint8_t* pB = Bq + (size_t)bn * 128 * KDIM + (size_t)srow * KDIM + gq * 16;
  uint8_t* const lA0 = &As[0][0] + tid * 16;   // 512*16 = 8 KB = 128 rows
  uint8_t* const lA1 = &As[1][0] + tid * 16;
  uint8_t* const lB0 = &Bs[0][0] + tid * 16;
  uint8_t* const lB1 = &Bs[1][0] + tid * 16;

  // A: 256 rows = 2 issues (128*KDIM = 131072 B apart); B: 128 rows = 1 issue.
#define STAGE(kt_, d_) do {                                                \
    const size_t ko_ = (size_t)(kt_) * 64;                                 \
    uint8_t* la_ = (d_) ? lA1 : lA0;                                       \
    uint8_t* lb_ = (d_) ? lB1 : lB0;                                       \
    gload_lds16(pA + ko_,          la_);                                   \
    gload_lds16(pA + ko_ + 131072, la_ + 8192);                            \
    gload_lds16(pB + ko_,          lb_);                                   \
  } while (0)

  // hoisted read addressing: row bases (buf0) + swizzled quad byte offsets
  const int swz = (lr >> 1) & 3;
  const int q0 = ((kb2 | 0) ^ swz) * 16;
  const int q1 = ((kb2 | 1) ^ swz) * 16;
  const uint8_t* const aR0 = &As[0][(wm * 64 +      lr) * 64];
  const uint8_t* const aR1 = &As[0][(wm * 64 + 32 + lr) * 64];
  const uint8_t* const bR0 = &Bs[0][(wn * 64 +      lr) * 64];
  const uint8_t* const bR1 = &Bs[0][(wn * 64 + 32 + lr) * 64];

#define RD(dst_, base_, bofs_) do {                                        \
    i32x4 lo_ = *(const i32x4*)((base_) + (bofs_) + q0);                   \
    i32x4 hi_ = *(const i32x4*)((base_) + (bofs_) + q1);                   \
    dst_ = __builtin_shufflevector(lo_, hi_, 0, 1, 2, 3, 4, 5, 6, 7);      \
  } while (0)

#define VMW3 asm volatile("s_waitcnt vmcnt(3)" ::: "memory")
#define VMW0 asm volatile("s_waitcnt vmcnt(0)" ::: "memory")

  // BODY consumes buf B_ (K-tile T_). Stage T_+1 into B_^1 FIRST, then counted
  // gate: vmcnt(3) = wait T_'s 3 loads, keep T_+1's 3 in flight across barriers.
#define BODY(B_, T_, DOSTAGE_, VMW_) do {                                  \
    if (DOSTAGE_) STAGE((T_) + 1, (B_) ^ 1);                               \
    VMW_;                                                                  \
    __builtin_amdgcn_s_barrier();                                          \
    MEMFENCE;                                                              \
    i32x8 b0, b1, a0, a1;                                                  \
    RD(b0, bR0, (B_) * 8192);                                              \
    RD(b1, bR1, (B_) * 8192);                                              \
    RD(a0, aR0, (B_) * 16384);                                             \
    RD(a1, aR1, (B_) * 16384);                                             \
    __builtin_amdgcn_s_setprio(1);                                         \
    acc[0][0] = __builtin_amdgcn_mfma_scale_f32_32x32x64_f8f6f4(           \
        a0, b0, acc[0][0], 0, 0, 0, 123, 0, 123);                          \
    acc[0][1] = __builtin_amdgcn_mfma_scale_f32_32x32x64_f8f6f4(           \
        a0, b1, acc[0][1], 0, 0, 0, 123, 0, 123);                          \
    acc[1][0] = __builtin_amdgcn_mfma_scale_f32_32x32x64_f8f6f4(           \
        a1, b0, acc[1][0], 0, 0, 0, 123, 0, 123);                          \
    acc[1][1] = __builtin_amdgcn_mfma_scale_f32_32x32x64_f8f6f4(           \
        a1, b1, acc[1][1], 0, 0, 0, 123, 0, 123);                          \
    __builtin_amdgcn_s_setprio(0);                                         \
    MEMFENCE;                                                              \
    __builtin_amdgcn_s_barrier();                                          \
    MEMFENCE;                                                              \
  } while (0)

  STAGE(0, 0);   // body 0's vmcnt(3) gate covers tile 0 (6 outstanding -> 3)

#pragma unroll 1
  for (int ktp = 0; ktp < 8; ++ktp) {
    BODY(0, 2 * ktp,     true,            VMW3);
    if (ktp < 7) BODY(1, 2 * ktp + 1, true, VMW3);
  }
  BODY(1, 15, false, VMW0);
#undef STAGE
#undef RD
#undef BODY
#undef VMW3
#undef VMW0

  // ---- epilogue: fused softmax stats per 64-col wave chunk ----
  // C/D 32x32 layout: col = lane&31, row = (reg&3) + 8*(reg>>2) + 4*(lane>>5)
  const int chunk = bn * 2 + wn;
  const int colbase = bn * 128 + wn * 64;
  float bov0 = bias[colbase + lr];
  float bov1 = bias[colbase + 32 + lr];
#pragma unroll
  for (int m = 0; m < 2; ++m) {
#pragma unroll
    for (int reg = 0; reg < 16; ++reg) {
      int rowg = bm * 256 + wm * 64 + m * 32 + (reg & 3) + 8 * (reg >> 2) + 4 * kb;
      float v0 = acc[m][0][reg] + bov0;
      float v1 = acc[m][1][reg] + bov1;
      float mv = fmaxf(v0, v1);
#pragma unroll
      for (int sft = 1; sft < 32; sft <<= 1) mv = fmaxf(mv, __shfl_xor(mv, sft));
      float se = __expf(v0 - mv) + __expf(v1 - mv);
#pragma unroll
      for (int sft = 1; sft < 32; sft <<= 1) se += __shfl_xor(se, sft);
      if (lr == 0) {
        pmax[(size_t)rowg * PSTRIDE + chunk] = mv;
        psum[(size_t)rowg * PSTRIDE + chunk] = se;
      }
      int cw = target[rowg] - colbase;
      if (cw >= 0 && cw < 64 && lr == (cw & 31)) {
        tlog[rowg] = (cw < 32) ? v0 : v1;
      }
    }
  }
}

// ---------------- combine per-chunk stats -> nll per row ----------------
__global__ void k_reduce_nll(const float* __restrict__ pmax,
                             const float* __restrict__ psum,
                             const float* __restrict__ tlog,
                             float* __restrict__ nll) {
  int row = blockIdx.x;
  int lane = threadIdx.x; // 64
  float M = -1e30f;
  for (int ch = lane; ch < NCHUNK; ch += 64) M = fmaxf(M, pmax[(size_t)row * PSTRIDE + ch]);
#pragma unroll
  for (int s = 1; s < 64; s <<= 1) M = fmaxf(M, __shfl_xor(M, s));
  float L = 0.f;
  for (int ch = lane; ch < NCHUNK; ch += 64)
    L += __expf(pmax[(size_t)row * PSTRIDE + ch] - M) * psum[(size_t)row * PSTRIDE + ch];
#pragma unroll
  for (int s = 1; s < 64; s <<= 1) L += __shfl_xor(L, s);
  if (lane == 0) nll[row] = -(tlog[row] - M - logf(L));
}

// ---------------- masked per-step mean -> scalar loss ----------------
__global__ void k_loss(const int* __restrict__ target,
                       const float* __restrict__ nll,
                       float* __restrict__ out) {
  __shared__ float red[SS];
  int s = threadIdx.x; // 512
  float sl = 0.f, cnt = 0.f;
#pragma unroll
  for (int b = 0; b < NB; ++b) {
    int idx = b * SS + s;
    if (target[idx] != 0) { sl += nll[idx]; cnt += 1.f; }
  }
  red[s] = sl / fmaxf(cnt, 1.f);
  __syncthreads();
  for (int st = 256; st > 0; st >>= 1) {
    if (s < st) red[s] += red[s + st];
    __syncthreads();
  }
  if (s == 0) out[0] = red[0] / (float)SS;
}

// ---------------- launch ----------------
extern "C" void kernel_launch(void* const* d_in, const int* in_sizes, int n_in,
                              void* d_out, int out_size, void* d_ws, size_t ws_size,
                              hipStream_t stream) {
  (void)in_sizes; (void)n_in; (void)out_size; (void)ws_size;
  const int*   text   = (const int*)d_in[0];
  const int*   target = (const int*)d_in[1];
  const float* embed  = (const float*)d_in[2];
  const float* W1     = (const float*)d_in[3];
  const float* b1     = (const float*)d_in[4];
  const float* W2     = (const float*)d_in[5];
  const float* b2     = (const float*)d_in[6];
  const float* Wo     = (const float*)d_in[7];
  const float* bo     = (const float*)d_in[8];
  float* out = (float*)d_out;
  char* ws = (char*)d_ws;

  const size_t SZ_E = (size_t)MTOK * KDIM * 2;          // 16.78 MB (bf16)
  unsigned short* E   = (unsigned short*)(ws);
  unsigned short* H1  = (unsigned short*)(ws + SZ_E);
  uint8_t*        H2Q = (uint8_t*)(ws + 2 * SZ_E);      // fp8, 8.39 MB
  char* p = ws + 2 * SZ_E + (size_t)MTOK * KDIM;
  unsigned short* W1t = (unsigned short*)p;  p += (size_t)HID * HID * 2;
  unsigned short* W2t = (unsigned short*)p;  p += (size_t)HID * HID * 2;
  uint8_t*        WoQ = (uint8_t*)p;         p += (size_t)VOCAB * HID;   // fp8, 32.77 MB
  float* tlog = (float*)p;                   p += (size_t)MTOK * 4;
  float* nll  = (float*)p;
  float* pmax = (float*)E;   // E dead after GEMM1
  float* psum = (float*)H1;  // H1 dead after GEMM2

  k_transpose_bf16<<<dim3(HID / 32, HID / 32), 256, 0, stream>>>(W1, W1t, HID, HID);
  k_transpose_bf16<<<dim3(HID / 32, HID / 32), 256, 0, stream>>>(W2, W2t, HID, HID);
  k_transpose_fp8 <<<dim3(VOCAB / 32, HID / 32), 256, 0, stream>>>(Wo, WoQ, HID, VOCAB);
  k_gather_e<<<MTOK, 256, 0, stream>>>(text, embed, E);

  k_gemm_ffn<0><<<dim3(HID / 128, MTOK / 128), 256, 0, stream>>>(E, W1t, b1, (void*)H1, HID);
  k_gemm_ffn<1><<<dim3(HID / 128, MTOK / 128), 256, 0, stream>>>(H1, W2t, b2, (void*)H2Q, HID);

  k_gemm_vocab_mx<<<dim3((MTOK / 256) * (VOCAB / 128)), 512, 0, stream>>>(
      H2Q, WoQ, bo, pmax, psum, tlog, target);

  k_reduce_nll<<<MTOK, 64, 0, stream>>>(pmax, psum, tlog, nll);
  k_loss<<<1, SS, 0, stream>>>(target, nll, out);
}

// Round 14
// 568.966 us; speedup vs baseline: 1.7139x; 1.1278x over previous
//
#include <hip/hip_runtime.h>
#include <cstdint>
#include <cstddef>

// ---------------- problem constants ----------------
#define VOCAB 32000
#define EMB   256
#define HID   1024
#define NB    16      // batch
#define SS    512     // seq
#define MTOK  (NB*SS) // 8192 tokens
#define KDIM  1024    // NM1*EMB = HID
#define NCHUNK 500    // 32000 / 64 cols per chunk
#define PSTRIDE 512   // padded chunk stride

typedef __bf16 bf16_t;
typedef bf16_t bf16x8 __attribute__((ext_vector_type(8)));
typedef float  f32x4  __attribute__((ext_vector_type(4)));
typedef float  f32x16 __attribute__((ext_vector_type(16)));
typedef int    i32x4  __attribute__((ext_vector_type(4)));
typedef int    i32x8  __attribute__((ext_vector_type(8)));

__device__ __forceinline__ unsigned short f32_to_bf16(float f) {
  union { float f; unsigned int u; } v; v.f = f;
  unsigned int u = v.u;
  unsigned int r = (u + 0x7FFFu + ((u >> 16) & 1u)) >> 16; // RNE
  return (unsigned short)r;
}

// f32 -> OCP e4m3fn, RNE, software (input assumed |x| <= 448)
__device__ __forceinline__ uint8_t f32_to_e4m3(float x) {
  union { float f; uint32_t u; } v; v.f = x;
  uint32_t s = (v.u >> 24) & 0x80u;
  int e = (int)((v.u >> 23) & 0xffu) - 127;
  uint32_t m = v.u & 0x7fffffu;
  if (e < -9) return (uint8_t)s;                  // -> 0
  if (e >= -6) {                                  // normal range
    uint32_t keep = m >> 20;
    uint32_t rest = m & 0xfffffu;
    keep += (rest > 0x80000u) || (rest == 0x80000u && (keep & 1u));
    if (keep == 8u) { keep = 0u; e += 1; }
    int code = ((e + 7) << 3) | (int)keep;
    if (code >= 0x7f) code = 0x7e;                // clamp to 448 (avoid NaN)
    return (uint8_t)(s | (uint32_t)code);
  }
  // subnormal
  uint32_t full = 0x800000u | m;
  int shift = 20 + (-6 - e);                      // 21..23
  uint32_t keep = full >> shift;
  uint32_t rest = full & ((1u << shift) - 1u);
  uint32_t half = 1u << (shift - 1);
  keep += (rest > half) || (rest == half && (keep & 1u));
  if (keep >= 8u) return (uint8_t)(s | 0x08u);
  return (uint8_t)(s | keep);
}

__device__ __forceinline__ void gload_lds16(const void* gsrc, void* ldst) {
  __builtin_amdgcn_global_load_lds(
      (__attribute__((address_space(1))) void*)gsrc,
      (__attribute__((address_space(3))) void*)ldst,
      16, 0, 0);
}

// Fragment-major record layout (per 32-row block rb, per K64-tile kt):
// 2048-B record at ((rb*16 + kt)*2048). Lane l's fragment bytes j (0..31):
//   src = Mat[row = 32*rb + (l&31)][kbyte = 64*kt + (l>>5)*32 + j]
//   j<16  -> record[l*16 + j]
//   j>=16 -> record[1024 + l*16 + (j-16)]
// A wave loads a frag with 2 coalesced global_load_dwordx4 (ofs 0 and 1024).

// ---------------- transpose + convert: in[R][C] f32 -> out[C][R] (bf16) ----------------
__global__ void k_transpose_bf16(const float* __restrict__ in,
                                 unsigned short* __restrict__ out,
                                 int R, int C) {
  __shared__ float tile[32][33];
  int bc = blockIdx.x * 32, br = blockIdx.y * 32;
  int tx = threadIdx.x & 31, ty = threadIdx.x >> 5;
#pragma unroll
  for (int i = 0; i < 32; i += 8)
    tile[ty + i][tx] = in[(size_t)(br + ty + i) * C + (bc + tx)];
  __syncthreads();
#pragma unroll
  for (int i = 0; i < 32; i += 8)
    out[(size_t)(bc + ty + i) * R + (br + tx)] = f32_to_bf16(tile[tx][ty + i]);
}

// ---------------- Wo -> fragment-major fp8 records ----------------
// grid (VOCAB/128, HID/64), 256 threads. Wo is [HID][VOCAB] f32.
__global__ void k_wo_frag(const float* __restrict__ Wo, uint8_t* __restrict__ Bf) {
  __shared__ uint8_t tile[64][128];  // [k-local][v-local]
  const int v0 = blockIdx.x * 128, k0 = blockIdx.y * 64;
  const int tid = threadIdx.x;
  // coalesced read: 8 iters x (8 rows x 32 float4)
#pragma unroll
  for (int rr = 0; rr < 8; ++rr) {
    int row = rr * 8 + (tid >> 5);
    const float4 f = *(const float4*)&Wo[(size_t)(k0 + row) * VOCAB + v0 + (tid & 31) * 4];
    int vb = (tid & 31) * 4;
    tile[row][vb + 0] = f32_to_e4m3(f.x * 16.0f);
    tile[row][vb + 1] = f32_to_e4m3(f.y * 16.0f);
    tile[row][vb + 2] = f32_to_e4m3(f.z * 16.0f);
    tile[row][vb + 3] = f32_to_e4m3(f.w * 16.0f);
  }
  __syncthreads();
  // write 4 records: rec = tid>>6 (v-block), l = tid&63
  const int rec = tid >> 6, l = tid & 63;
  const int vloc = rec * 32 + (l & 31);
  const int kb = (l >> 5) * 32;
  uint8_t* out = Bf + ((size_t)((blockIdx.x * 4 + rec) * 16 + blockIdx.y)) * 2048 + l * 16;
  union { uint8_t b[16]; i32x4 v; } lo, hi;
#pragma unroll
  for (int j = 0; j < 16; ++j) {
    lo.b[j] = tile[kb + j][vloc];
    hi.b[j] = tile[kb + 16 + j][vloc];
  }
  *(i32x4*)(out)        = lo.v;
  *(i32x4*)(out + 1024) = hi.v;
}

// ---------------- embedding gather ----------------
__global__ void k_gather_e(const int* __restrict__ text,
                           const float* __restrict__ embed,
                           unsigned short* __restrict__ E) {
  int t = blockIdx.x;
  int b = t >> 9, s = t & 511;
  int d = threadIdx.x; // 0..255
#pragma unroll
  for (int j = 0; j < 4; ++j) {
    int sidx = s + j - 4;
    int tok = (sidx >= 0) ? text[b * SS + sidx] : 0;
    float val = (tok != 0) ? embed[(size_t)tok * EMB + d] : 0.0f;
    E[(size_t)t * KDIM + j * EMB + d] = f32_to_bf16(val);
  }
}

// ---------------- FFN GEMM (128x128 tile; OUTQ=1 -> fp8 fragment-major records) -------
template<int OUTQ>
__global__ __launch_bounds__(256)
void k_gemm_ffn(const unsigned short* __restrict__ A,
                const unsigned short* __restrict__ Bt,
                const float* __restrict__ bias,
                void* __restrict__ Hout, int N) {
  __shared__ unsigned short As[128 * 32];
  __shared__ unsigned short Bs[128 * 32];
  const int tid  = threadIdx.x;
  const int bn   = blockIdx.x, bm = blockIdx.y;
  const int lane = tid & 63, wid = tid >> 6;
  const int wm = wid >> 1, wn = wid & 1;
  const int g = lane >> 4, c = lane & 15;

  f32x4 acc[4][4];
#pragma unroll
  for (int m = 0; m < 4; ++m)
#pragma unroll
    for (int n = 0; n < 4; ++n) { f32x4 z = {0.f, 0.f, 0.f, 0.f}; acc[m][n] = z; }

  const int arow = tid >> 2;
  const int slotb = ((tid & 3) ^ ((tid >> 3) & 3)) * 16;
  const char* gA0 = (const char*)A + ((size_t)(bm * 128 + arow) * KDIM) * 2 + slotb;
  const char* gA1 = gA0 + (size_t)64 * KDIM * 2;
  const char* gB0 = (const char*)Bt + ((size_t)(bn * 128 + arow) * KDIM) * 2 + slotb;
  const char* gB1 = gB0 + (size_t)64 * KDIM * 2;
  char* lA = (char*)As + tid * 16;
  char* lB = (char*)Bs + tid * 16;

  const int rs = (g ^ ((c >> 1) & 3)) * 8;

  for (int kt = 0; kt < KDIM / 32; ++kt) {
    const int kb = kt * 64;
    gload_lds16(gA0 + kb, lA);
    gload_lds16(gA1 + kb, lA + 4096);
    gload_lds16(gB0 + kb, lB);
    gload_lds16(gB1 + kb, lB + 4096);
    __syncthreads();

    bf16x8 af[4], bf[4];
#pragma unroll
    for (int m = 0; m < 4; ++m)
      af[m] = *(const bf16x8*)&As[(wm * 64 + m * 16 + c) * 32 + rs];
#pragma unroll
    for (int n = 0; n < 4; ++n)
      bf[n] = *(const bf16x8*)&Bs[(wn * 64 + n * 16 + c) * 32 + rs];
#pragma unroll
    for (int m = 0; m < 4; ++m)
#pragma unroll
      for (int n = 0; n < 4; ++n)
        acc[m][n] = __builtin_amdgcn_mfma_f32_16x16x32_bf16(af[m], bf[n], acc[m][n], 0, 0, 0);
    __syncthreads();
  }

#pragma unroll
  for (int n = 0; n < 4; ++n) {
    int colg = bn * 128 + wn * 64 + n * 16 + c;
    float bv = bias[colg];
#pragma unroll
    for (int m = 0; m < 4; ++m)
#pragma unroll
      for (int j = 0; j < 4; ++j) {
        int rowg = bm * 128 + wm * 64 + m * 16 + g * 4 + j;
        float v = acc[m][n][j] + bv;
        v = v > 0.f ? v : 0.f;
        if constexpr (OUTQ == 0) {
          ((unsigned short*)Hout)[(size_t)rowg * N + colg] = f32_to_bf16(v);
        } else {
          // fragment-major record store (see layout comment above)
          int ra = rowg >> 5, kt2 = colg >> 6;
          int l = (rowg & 31) + ((colg >> 5) & 1) * 32;
          int jj = colg & 31;
          size_t off = ((size_t)(ra * 16 + kt2)) * 2048 +
                       ((jj & 16) ? 1024 : 0) + l * 16 + (jj & 15);
          ((uint8_t*)Hout)[off] = f32_to_e4m3(v * 16.0f);
        }
      }
  }
}

// ---------------- vocab GEMM: MX-fp8, NO LDS, NO barriers (streaming frags) ----------
// Operands come from fragment-major records via coalesced global_load_dwordx4.
// 4 waves/block (2Mx2N), per-wave out 64x64, per-block 128x128. Waves are fully
// independent -> natural phase diversity (fix for the measured pipe-sum lockstep);
// latency hidden by TLP (~150 unified regs -> ~12-13 waves/CU). L1 dedups the
// 2x operand sharing within a block. setprio in its proven independent-wave regime.
__global__ __launch_bounds__(256, 2)
void k_gemm_vocab_mx(const uint8_t* __restrict__ Af,   // [256][16] records (A frags)
                     const uint8_t* __restrict__ Bf,   // [1000][16] records (B frags)
                     const float* __restrict__ bias,
                     float* __restrict__ pmax, float* __restrict__ psum,
                     float* __restrict__ tlog, const int* __restrict__ target) {
  const int tid  = threadIdx.x;
  const int lane = tid & 63, wid = tid >> 6;   // 4 waves
  const int wm = wid >> 1, wn = wid & 1;       // 2(M) x 2(N)
  const int lr = lane & 31, kb = lane >> 5;

  // XCD-chunked swizzle; grid = 16000 = 64(bm) x 250(bn)
  const int t   = blockIdx.x;
  const int xcd = t & 7, i = t >> 3;           // i 0..1999
  const int bm  = xcd * 8 + (i & 7);           // 0..63
  const int bn  = i >> 3;                      // 0..249

  f32x16 acc[2][2];
#pragma unroll
  for (int m = 0; m < 2; ++m)
#pragma unroll
    for (int n = 0; n < 2; ++n)
#pragma unroll
      for (int e = 0; e < 16; ++e) acc[m][n][e] = 0.f;

  // per-lane record pointers (advance 2048 B per K-tile)
  const uint8_t* pa0 = Af + ((size_t)(bm * 4 + wm * 2 + 0) * 16) * 2048 + lane * 16;
  const uint8_t* pa1 = Af + ((size_t)(bm * 4 + wm * 2 + 1) * 16) * 2048 + lane * 16;
  const uint8_t* pb0 = Bf + ((size_t)(bn * 4 + wn * 2 + 0) * 16) * 2048 + lane * 16;
  const uint8_t* pb1 = Bf + ((size_t)(bn * 4 + wn * 2 + 1) * 16) * 2048 + lane * 16;

#pragma unroll 1
  for (int kt = 0; kt < 16; ++kt) {
    i32x4 a0l = *(const i32x4*)(pa0);
    i32x4 a0h = *(const i32x4*)(pa0 + 1024);
    i32x4 a1l = *(const i32x4*)(pa1);
    i32x4 a1h = *(const i32x4*)(pa1 + 1024);
    i32x4 b0l = *(const i32x4*)(pb0);
    i32x4 b0h = *(const i32x4*)(pb0 + 1024);
    i32x4 b1l = *(const i32x4*)(pb1);
    i32x4 b1h = *(const i32x4*)(pb1 + 1024);
    pa0 += 2048; pa1 += 2048; pb0 += 2048; pb1 += 2048;

    i32x8 a0 = __builtin_shufflevector(a0l, a0h, 0, 1, 2, 3, 4, 5, 6, 7);
    i32x8 a1 = __builtin_shufflevector(a1l, a1h, 0, 1, 2, 3, 4, 5, 6, 7);
    i32x8 b0 = __builtin_shufflevector(b0l, b0h, 0, 1, 2, 3, 4, 5, 6, 7);
    i32x8 b1 = __builtin_shufflevector(b1l, b1h, 0, 1, 2, 3, 4, 5, 6, 7);

    __builtin_amdgcn_s_setprio(1);
    acc[0][0] = __builtin_amdgcn_mfma_scale_f32_32x32x64_f8f6f4(
        a0, b0, acc[0][0], 0, 0, 0, 123, 0, 123);
    acc[0][1] = __builtin_amdgcn_mfma_scale_f32_32x32x64_f8f6f4(
        a0, b1, acc[0][1], 0, 0, 0, 123, 0, 123);
    acc[1][0] = __builtin_amdgcn_mfma_scale_f32_32x32x64_f8f6f4(
        a1, b0, acc[1][0], 0, 0, 0, 123, 0, 123);
    acc[1][1] = __builtin_amdgcn_mfma_scale_f32_32x32x64_f8f6f4(
        a1, b1, acc[1][1], 0, 0, 0, 123, 0, 123);
    __builtin_amdgcn_s_setprio(0);
  }

  // ---- epilogue: fused softmax stats per 64-col wave chunk ----
  // C/D 32x32 layout: col = lane&31, row = (reg&3) + 8*(reg>>2) + 4*(lane>>5)
  const int chunk = bn * 2 + wn;
  const int colbase = bn * 128 + wn * 64;
  float bov0 = bias[colbase + lr];
  float bov1 = bias[colbase + 32 + lr];
#pragma unroll
  for (int m = 0; m < 2; ++m) {
#pragma unroll
    for (int reg = 0; reg < 16; ++reg) {
      int rowg = bm * 128 + wm * 64 + m * 32 + (reg & 3) + 8 * (reg >> 2) + 4 * kb;
      float v0 = acc[m][0][reg] + bov0;
      float v1 = acc[m][1][reg] + bov1;
      float mv = fmaxf(v0, v1);
#pragma unroll
      for (int sft = 1; sft < 32; sft <<= 1) mv = fmaxf(mv, __shfl_xor(mv, sft));
      float se = __expf(v0 - mv) + __expf(v1 - mv);
#pragma unroll
      for (int sft = 1; sft < 32; sft <<= 1) se += __shfl_xor(se, sft);
      if (lr == 0) {
        pmax[(size_t)rowg * PSTRIDE + chunk] = mv;
        psum[(size_t)rowg * PSTRIDE + chunk] = se;
      }
      int cw = target[rowg] - colbase;
      if (cw >= 0 && cw < 64 && lr == (cw & 31)) {
        tlog[rowg] = (cw < 32) ? v0 : v1;
      }
    }
  }
}

// ---------------- combine per-chunk stats -> nll per row ----------------
__global__ void k_reduce_nll(const float* __restrict__ pmax,
                             const float* __restrict__ psum,
                             const float* __restrict__ tlog,
                             float* __restrict__ nll) {
  int row = blockIdx.x;
  int lane = threadIdx.x; // 64
  float M = -1e30f;
  for (int ch = lane; ch < NCHUNK; ch += 64) M = fmaxf(M, pmax[(size_t)row * PSTRIDE + ch]);
#pragma unroll
  for (int s = 1; s < 64; s <<= 1) M = fmaxf(M, __shfl_xor(M, s));
  float L = 0.f;
  for (int ch = lane; ch < NCHUNK; ch += 64)
    L += __expf(pmax[(size_t)row * PSTRIDE + ch] - M) * psum[(size_t)row * PSTRIDE + ch];
#pragma unroll
  for (int s = 1; s < 64; s <<= 1) L += __shfl_xor(L, s);
  if (lane == 0) nll[row] = -(tlog[row] - M - logf(L));
}

// ---------------- masked per-step mean -> scalar loss ----------------
__global__ void k_loss(const int* __restrict__ target,
                       const float* __restrict__ nll,
                       float* __restrict__ out) {
  __shared__ float red[SS];
  int s = threadIdx.x; // 512
  float sl = 0.f, cnt = 0.f;
#pragma unroll
  for (int b = 0; b < NB; ++b) {
    int idx = b * SS + s;
    if (target[idx] != 0) { sl += nll[idx]; cnt += 1.f; }
  }
  red[s] = sl / fmaxf(cnt, 1.f);
  __syncthreads();
  for (int st = 256; st > 0; st >>= 1) {
    if (s < st) red[s] += red[s + st];
    __syncthreads();
  }
  if (s == 0) out[0] = red[0] / (float)SS;
}

// ---------------- launch ----------------
extern "C" void kernel_launch(void* const* d_in, const int* in_sizes, int n_in,
                              void* d_out, int out_size, void* d_ws, size_t ws_size,
                              hipStream_t stream) {
  (void)in_sizes; (void)n_in; (void)out_size; (void)ws_size;
  const int*   text   = (const int*)d_in[0];
  const int*   target = (const int*)d_in[1];
  const float* embed  = (const float*)d_in[2];
  const float* W1     = (const float*)d_in[3];
  const float* b1     = (const float*)d_in[4];
  const float* W2     = (const float*)d_in[5];
  const float* b2     = (const float*)d_in[6];
  const float* Wo     = (const float*)d_in[7];
  const float* bo     = (const float*)d_in[8];
  float* out = (float*)d_out;
  char* ws = (char*)d_ws;

  const size_t SZ_E = (size_t)MTOK * KDIM * 2;          // 16.78 MB (bf16)
  unsigned short* E   = (unsigned short*)(ws);
  unsigned short* H1  = (unsigned short*)(ws + SZ_E);
  uint8_t*        H2Q = (uint8_t*)(ws + 2 * SZ_E);      // fp8 A-records, 8.39 MB
  char* p = ws + 2 * SZ_E + (size_t)MTOK * KDIM;
  unsigned short* W1t = (unsigned short*)p;  p += (size_t)HID * HID * 2;
  unsigned short* W2t = (unsigned short*)p;  p += (size_t)HID * HID * 2;
  uint8_t*        WoQ = (uint8_t*)p;         p += (size_t)VOCAB * HID;   // fp8 B-records, 32.77 MB
  float* tlog = (float*)p;                   p += (size_t)MTOK * 4;
  float* nll  = (float*)p;
  float* pmax = (float*)E;   // E dead after GEMM1
  float* psum = (float*)H1;  // H1 dead after GEMM2

  k_transpose_bf16<<<dim3(HID / 32, HID / 32), 256, 0, stream>>>(W1, W1t, HID, HID);
  k_transpose_bf16<<<dim3(HID / 32, HID / 32), 256, 0, stream>>>(W2, W2t, HID, HID);
  k_wo_frag<<<dim3(VOCAB / 128, HID / 64), 256, 0, stream>>>(Wo, WoQ);
  k_gather_e<<<MTOK, 256, 0, stream>>>(text, embed, E);

  k_gemm_ffn<0><<<dim3(HID / 128, MTOK / 128), 256, 0, stream>>>(E, W1t, b1, (void*)H1, HID);
  k_gemm_ffn<1><<<dim3(HID / 128, MTOK / 128), 256, 0, stream>>>(H1, W2t, b2, (void*)H2Q, HID);

  k_gemm_vocab_mx<<<dim3((MTOK / 128) * (VOCAB / 128)), 256, 0, stream>>>(
      H2Q, WoQ, bo, pmax, psum, tlog, target);

  k_reduce_nll<<<MTOK, 64, 0, stream>>>(pmax, psum, tlog, nll);
  k_loss<<<1, SS, 0, stream>>>(target, nll, out);
}

// Round 15
// 473.688 us; speedup vs baseline: 2.0586x; 1.2011x over previous
//
#include <hip/hip_runtime.h>
#include <cstdint>
#include <cstddef>

// ---------------- problem constants ----------------
#define VOCAB 32000
#define EMB   256
#define HID   1024
#define NB    16      // batch
#define SS    512     // seq
#define MTOK  (NB*SS) // 8192 tokens
#define KDIM  1024    // NM1*EMB = HID
#define NCHUNK 500    // 32000 / 64 cols per chunk
#define PSTRIDE 512   // padded chunk stride

typedef __bf16 bf16_t;
typedef bf16_t bf16x8 __attribute__((ext_vector_type(8)));
typedef float  f32x4  __attribute__((ext_vector_type(4)));
typedef float  f32x16 __attribute__((ext_vector_type(16)));
typedef int    i32x4  __attribute__((ext_vector_type(4)));
typedef int    i32x8  __attribute__((ext_vector_type(8)));

__device__ __forceinline__ unsigned short f32_to_bf16(float f) {
  union { float f; unsigned int u; } v; v.f = f;
  unsigned int u = v.u;
  unsigned int r = (u + 0x7FFFu + ((u >> 16) & 1u)) >> 16; // RNE
  return (unsigned short)r;
}

// f32 -> OCP e4m3fn, RNE, software (input assumed |x| <= 448)
__device__ __forceinline__ uint8_t f32_to_e4m3(float x) {
  union { float f; uint32_t u; } v; v.f = x;
  uint32_t s = (v.u >> 24) & 0x80u;
  int e = (int)((v.u >> 23) & 0xffu) - 127;
  uint32_t m = v.u & 0x7fffffu;
  if (e < -9) return (uint8_t)s;                  // -> 0
  if (e >= -6) {                                  // normal range
    uint32_t keep = m >> 20;
    uint32_t rest = m & 0xfffffu;
    keep += (rest > 0x80000u) || (rest == 0x80000u && (keep & 1u));
    if (keep == 8u) { keep = 0u; e += 1; }
    int code = ((e + 7) << 3) | (int)keep;
    if (code >= 0x7f) code = 0x7e;                // clamp to 448 (avoid NaN)
    return (uint8_t)(s | (uint32_t)code);
  }
  // subnormal
  uint32_t full = 0x800000u | m;
  int shift = 20 + (-6 - e);                      // 21..23
  uint32_t keep = full >> shift;
  uint32_t rest = full & ((1u << shift) - 1u);
  uint32_t half = 1u << (shift - 1);
  keep += (rest > half) || (rest == half && (keep & 1u));
  if (keep >= 8u) return (uint8_t)(s | 0x08u);
  return (uint8_t)(s | keep);
}

__device__ __forceinline__ void gload_lds16(const void* gsrc, void* ldst) {
  __builtin_amdgcn_global_load_lds(
      (__attribute__((address_space(1))) void*)gsrc,
      (__attribute__((address_space(3))) void*)ldst,
      16, 0, 0);
}

// Fragment-major record layout (per 32-row block rb, per K64-tile kt):
// 2048-B record at ((rb*16 + kt)*2048). Lane l's fragment bytes j (0..31):
//   src = Mat[row = 32*rb + (l&31)][kbyte = 64*kt + (l>>5)*32 + j]
//   j<16  -> record[l*16 + j]
//   j>=16 -> record[1024 + l*16 + (j-16)]
// A wave loads a frag with 2 coalesced global_load_dwordx4 (ofs 0 and 1024).

// ---------------- transpose + convert: in[R][C] f32 -> out[C][R] (bf16) ----------------
__global__ void k_transpose_bf16(const float* __restrict__ in,
                                 unsigned short* __restrict__ out,
                                 int R, int C) {
  __shared__ float tile[32][33];
  int bc = blockIdx.x * 32, br = blockIdx.y * 32;
  int tx = threadIdx.x & 31, ty = threadIdx.x >> 5;
#pragma unroll
  for (int i = 0; i < 32; i += 8)
    tile[ty + i][tx] = in[(size_t)(br + ty + i) * C + (bc + tx)];
  __syncthreads();
#pragma unroll
  for (int i = 0; i < 32; i += 8)
    out[(size_t)(bc + ty + i) * R + (br + tx)] = f32_to_bf16(tile[tx][ty + i]);
}

// ---------------- Wo -> fragment-major fp8 records ----------------
// grid (VOCAB/128, HID/64), 256 threads. Wo is [HID][VOCAB] f32.
__global__ void k_wo_frag(const float* __restrict__ Wo, uint8_t* __restrict__ Bf) {
  __shared__ uint8_t tile[64][128];  // [k-local][v-local]
  const int v0 = blockIdx.x * 128, k0 = blockIdx.y * 64;
  const int tid = threadIdx.x;
#pragma unroll
  for (int rr = 0; rr < 8; ++rr) {
    int row = rr * 8 + (tid >> 5);
    const float4 f = *(const float4*)&Wo[(size_t)(k0 + row) * VOCAB + v0 + (tid & 31) * 4];
    int vb = (tid & 31) * 4;
    tile[row][vb + 0] = f32_to_e4m3(f.x * 16.0f);
    tile[row][vb + 1] = f32_to_e4m3(f.y * 16.0f);
    tile[row][vb + 2] = f32_to_e4m3(f.z * 16.0f);
    tile[row][vb + 3] = f32_to_e4m3(f.w * 16.0f);
  }
  __syncthreads();
  const int rec = tid >> 6, l = tid & 63;
  const int vloc = rec * 32 + (l & 31);
  const int kb = (l >> 5) * 32;
  uint8_t* out = Bf + ((size_t)((blockIdx.x * 4 + rec) * 16 + blockIdx.y)) * 2048 + l * 16;
  union { uint8_t b[16]; i32x4 v; } lo, hi;
#pragma unroll
  for (int j = 0; j < 16; ++j) {
    lo.b[j] = tile[kb + j][vloc];
    hi.b[j] = tile[kb + 16 + j][vloc];
  }
  *(i32x4*)(out)        = lo.v;
  *(i32x4*)(out + 1024) = hi.v;
}

// ---------------- embedding gather ----------------
__global__ void k_gather_e(const int* __restrict__ text,
                           const float* __restrict__ embed,
                           unsigned short* __restrict__ E) {
  int t = blockIdx.x;
  int b = t >> 9, s = t & 511;
  int d = threadIdx.x; // 0..255
#pragma unroll
  for (int j = 0; j < 4; ++j) {
    int sidx = s + j - 4;
    int tok = (sidx >= 0) ? text[b * SS + sidx] : 0;
    float val = (tok != 0) ? embed[(size_t)tok * EMB + d] : 0.0f;
    E[(size_t)t * KDIM + j * EMB + d] = f32_to_bf16(val);
  }
}

// ---------------- FFN GEMM (128x128 tile; OUTQ=1 -> fp8 fragment-major records) -------
template<int OUTQ>
__global__ __launch_bounds__(256)
void k_gemm_ffn(const unsigned short* __restrict__ A,
                const unsigned short* __restrict__ Bt,
                const float* __restrict__ bias,
                void* __restrict__ Hout, int N) {
  __shared__ unsigned short As[128 * 32];
  __shared__ unsigned short Bs[128 * 32];
  const int tid  = threadIdx.x;
  const int bn   = blockIdx.x, bm = blockIdx.y;
  const int lane = tid & 63, wid = tid >> 6;
  const int wm = wid >> 1, wn = wid & 1;
  const int g = lane >> 4, c = lane & 15;

  f32x4 acc[4][4];
#pragma unroll
  for (int m = 0; m < 4; ++m)
#pragma unroll
    for (int n = 0; n < 4; ++n) { f32x4 z = {0.f, 0.f, 0.f, 0.f}; acc[m][n] = z; }

  const int arow = tid >> 2;
  const int slotb = ((tid & 3) ^ ((tid >> 3) & 3)) * 16;
  const char* gA0 = (const char*)A + ((size_t)(bm * 128 + arow) * KDIM) * 2 + slotb;
  const char* gA1 = gA0 + (size_t)64 * KDIM * 2;
  const char* gB0 = (const char*)Bt + ((size_t)(bn * 128 + arow) * KDIM) * 2 + slotb;
  const char* gB1 = gB0 + (size_t)64 * KDIM * 2;
  char* lA = (char*)As + tid * 16;
  char* lB = (char*)Bs + tid * 16;

  const int rs = (g ^ ((c >> 1) & 3)) * 8;

  for (int kt = 0; kt < KDIM / 32; ++kt) {
    const int kb = kt * 64;
    gload_lds16(gA0 + kb, lA);
    gload_lds16(gA1 + kb, lA + 4096);
    gload_lds16(gB0 + kb, lB);
    gload_lds16(gB1 + kb, lB + 4096);
    __syncthreads();

    bf16x8 af[4], bf[4];
#pragma unroll
    for (int m = 0; m < 4; ++m)
      af[m] = *(const bf16x8*)&As[(wm * 64 + m * 16 + c) * 32 + rs];
#pragma unroll
    for (int n = 0; n < 4; ++n)
      bf[n] = *(const bf16x8*)&Bs[(wn * 64 + n * 16 + c) * 32 + rs];
#pragma unroll
    for (int m = 0; m < 4; ++m)
#pragma unroll
      for (int n = 0; n < 4; ++n)
        acc[m][n] = __builtin_amdgcn_mfma_f32_16x16x32_bf16(af[m], bf[n], acc[m][n], 0, 0, 0);
    __syncthreads();
  }

#pragma unroll
  for (int n = 0; n < 4; ++n) {
    int colg = bn * 128 + wn * 64 + n * 16 + c;
    float bv = bias[colg];
#pragma unroll
    for (int m = 0; m < 4; ++m)
#pragma unroll
      for (int j = 0; j < 4; ++j) {
        int rowg = bm * 128 + wm * 64 + m * 16 + g * 4 + j;
        float v = acc[m][n][j] + bv;
        v = v > 0.f ? v : 0.f;
        if constexpr (OUTQ == 0) {
          ((unsigned short*)Hout)[(size_t)rowg * N + colg] = f32_to_bf16(v);
        } else {
          // fragment-major record store (see layout comment above)
          int ra = rowg >> 5, kt2 = colg >> 6;
          int l = (rowg & 31) + ((colg >> 5) & 1) * 32;
          int jj = colg & 31;
          size_t off = ((size_t)(ra * 16 + kt2)) * 2048 +
                       ((jj & 16) ? 1024 : 0) + l * 16 + (jj & 15);
          ((uint8_t*)Hout)[off] = f32_to_e4m3(v * 16.0f);
        }
      }
  }
}

// ---------------- vocab GEMM: MX-fp8, NO LDS, NO barriers (streaming frags) ----------
// R15: epilogue drops max-stabilization (logits bounded ~|1|; worst case |18| --
// exp/f32 safe) -> ONE 5-step butterfly per (m,reg) instead of two, done with
// ds_swizzle literal patterns (no VALU addr math), and no pmax array at all.
__global__ __launch_bounds__(256, 2)
void k_gemm_vocab_mx(const uint8_t* __restrict__ Af,   // [256][16] records (A frags)
                     const uint8_t* __restrict__ Bf,   // [1000][16] records (B frags)
                     const float* __restrict__ bias,
                     float* __restrict__ psum,
                     float* __restrict__ tlog, const int* __restrict__ target) {
  const int tid  = threadIdx.x;
  const int lane = tid & 63, wid = tid >> 6;   // 4 waves
  const int wm = wid >> 1, wn = wid & 1;       // 2(M) x 2(N)
  const int lr = lane & 31, kb = lane >> 5;

  // XCD-chunked swizzle; grid = 16000 = 64(bm) x 250(bn)
  const int t   = blockIdx.x;
  const int xcd = t & 7, i = t >> 3;           // i 0..1999
  const int bm  = xcd * 8 + (i & 7);           // 0..63
  const int bn  = i >> 3;                      // 0..249

  f32x16 acc[2][2];
#pragma unroll
  for (int m = 0; m < 2; ++m)
#pragma unroll
    for (int n = 0; n < 2; ++n)
#pragma unroll
      for (int e = 0; e < 16; ++e) acc[m][n][e] = 0.f;

  // per-lane record pointers (advance 2048 B per K-tile)
  const uint8_t* pa0 = Af + ((size_t)(bm * 4 + wm * 2 + 0) * 16) * 2048 + lane * 16;
  const uint8_t* pa1 = Af + ((size_t)(bm * 4 + wm * 2 + 1) * 16) * 2048 + lane * 16;
  const uint8_t* pb0 = Bf + ((size_t)(bn * 4 + wn * 2 + 0) * 16) * 2048 + lane * 16;
  const uint8_t* pb1 = Bf + ((size_t)(bn * 4 + wn * 2 + 1) * 16) * 2048 + lane * 16;

#pragma unroll 1
  for (int kt = 0; kt < 16; ++kt) {
    i32x4 a0l = *(const i32x4*)(pa0);
    i32x4 a0h = *(const i32x4*)(pa0 + 1024);
    i32x4 a1l = *(const i32x4*)(pa1);
    i32x4 a1h = *(const i32x4*)(pa1 + 1024);
    i32x4 b0l = *(const i32x4*)(pb0);
    i32x4 b0h = *(const i32x4*)(pb0 + 1024);
    i32x4 b1l = *(const i32x4*)(pb1);
    i32x4 b1h = *(const i32x4*)(pb1 + 1024);
    pa0 += 2048; pa1 += 2048; pb0 += 2048; pb1 += 2048;

    i32x8 a0 = __builtin_shufflevector(a0l, a0h, 0, 1, 2, 3, 4, 5, 6, 7);
    i32x8 a1 = __builtin_shufflevector(a1l, a1h, 0, 1, 2, 3, 4, 5, 6, 7);
    i32x8 b0 = __builtin_shufflevector(b0l, b0h, 0, 1, 2, 3, 4, 5, 6, 7);
    i32x8 b1 = __builtin_shufflevector(b1l, b1h, 0, 1, 2, 3, 4, 5, 6, 7);

    __builtin_amdgcn_s_setprio(1);
    acc[0][0] = __builtin_amdgcn_mfma_scale_f32_32x32x64_f8f6f4(
        a0, b0, acc[0][0], 0, 0, 0, 123, 0, 123);
    acc[0][1] = __builtin_amdgcn_mfma_scale_f32_32x32x64_f8f6f4(
        a0, b1, acc[0][1], 0, 0, 0, 123, 0, 123);
    acc[1][0] = __builtin_amdgcn_mfma_scale_f32_32x32x64_f8f6f4(
        a1, b0, acc[1][0], 0, 0, 0, 123, 0, 123);
    acc[1][1] = __builtin_amdgcn_mfma_scale_f32_32x32x64_f8f6f4(
        a1, b1, acc[1][1], 0, 0, 0, 123, 0, 123);
    __builtin_amdgcn_s_setprio(0);
  }

  // ---- epilogue: per-64-col-chunk sum of exp (no max) ----
  // C/D 32x32 layout: col = lane&31, row = (reg&3) + 8*(reg>>2) + 4*(lane>>5)
  const int chunk = bn * 2 + wn;
  const int colbase = bn * 128 + wn * 64;
  float bov0 = bias[colbase + lr];
  float bov1 = bias[colbase + 32 + lr];
#pragma unroll
  for (int m = 0; m < 2; ++m) {
#pragma unroll
    for (int reg = 0; reg < 16; ++reg) {
      int rowg = bm * 128 + wm * 64 + m * 32 + (reg & 3) + 8 * (reg >> 2) + 4 * kb;
      float v0 = acc[m][0][reg] + bov0;
      float v1 = acc[m][1][reg] + bov1;
      float e = __expf(v0) + __expf(v1);
      // 5-step butterfly within each 32-lane group; literal BitMode patterns:
      // offset = (xor<<10) | 0x1F  (and=0x1F, or=0) -> lane ^= xor within group
      union { float f; int i; } a_, b_;
      a_.f = e; b_.i = __builtin_amdgcn_ds_swizzle(a_.i, 0x041F); e += b_.f;
      a_.f = e; b_.i = __builtin_amdgcn_ds_swizzle(a_.i, 0x081F); e += b_.f;
      a_.f = e; b_.i = __builtin_amdgcn_ds_swizzle(a_.i, 0x101F); e += b_.f;
      a_.f = e; b_.i = __builtin_amdgcn_ds_swizzle(a_.i, 0x201F); e += b_.f;
      a_.f = e; b_.i = __builtin_amdgcn_ds_swizzle(a_.i, 0x401F); e += b_.f;
      if (lr == 0) psum[(size_t)rowg * PSTRIDE + chunk] = e;
      int cw = target[rowg] - colbase;
      if (cw >= 0 && cw < 64 && lr == (cw & 31)) {
        tlog[rowg] = (cw < 32) ? v0 : v1;
      }
    }
  }
}

// ---------------- combine per-chunk sums -> nll per row ----------------
__global__ void k_reduce_nll(const float* __restrict__ psum,
                             const float* __restrict__ tlog,
                             float* __restrict__ nll) {
  int row = blockIdx.x;
  int lane = threadIdx.x; // 64
  float L = 0.f;
  for (int ch = lane; ch < NCHUNK; ch += 64)
    L += psum[(size_t)row * PSTRIDE + ch];
#pragma unroll
  for (int s = 1; s < 64; s <<= 1) L += __shfl_xor(L, s);
  if (lane == 0) nll[row] = logf(L) - tlog[row];
}

// ---------------- masked per-step mean -> scalar loss ----------------
__global__ void k_loss(const int* __restrict__ target,
                       const float* __restrict__ nll,
                       float* __restrict__ out) {
  __shared__ float red[SS];
  int s = threadIdx.x; // 512
  float sl = 0.f, cnt = 0.f;
#pragma unroll
  for (int b = 0; b < NB; ++b) {
    int idx = b * SS + s;
    if (target[idx] != 0) { sl += nll[idx]; cnt += 1.f; }
  }
  red[s] = sl / fmaxf(cnt, 1.f);
  __syncthreads();
  for (int st = 256; st > 0; st >>= 1) {
    if (s < st) red[s] += red[s + st];
    __syncthreads();
  }
  if (s == 0) out[0] = red[0] / (float)SS;
}

// ---------------- launch ----------------
extern "C" void kernel_launch(void* const* d_in, const int* in_sizes, int n_in,
                              void* d_out, int out_size, void* d_ws, size_t ws_size,
                              hipStream_t stream) {
  (void)in_sizes; (void)n_in; (void)out_size; (void)ws_size;
  const int*   text   = (const int*)d_in[0];
  const int*   target = (const int*)d_in[1];
  const float* embed  = (const float*)d_in[2];
  const float* W1     = (const float*)d_in[3];
  const float* b1     = (const float*)d_in[4];
  const float* W2     = (const float*)d_in[5];
  const float* b2     = (const float*)d_in[6];
  const float* Wo     = (const float*)d_in[7];
  const float* bo     = (const float*)d_in[8];
  float* out = (float*)d_out;
  char* ws = (char*)d_ws;

  const size_t SZ_E = (size_t)MTOK * KDIM * 2;          // 16.78 MB (bf16)
  unsigned short* E   = (unsigned short*)(ws);
  unsigned short* H1  = (unsigned short*)(ws + SZ_E);
  uint8_t*        H2Q = (uint8_t*)(ws + 2 * SZ_E);      // fp8 A-records, 8.39 MB
  char* p = ws + 2 * SZ_E + (size_t)MTOK * KDIM;
  unsigned short* W1t = (unsigned short*)p;  p += (size_t)HID * HID * 2;
  unsigned short* W2t = (unsigned short*)p;  p += (size_t)HID * HID * 2;
  uint8_t*        WoQ = (uint8_t*)p;         p += (size_t)VOCAB * HID;   // fp8 B-records, 32.77 MB
  float* tlog = (float*)p;                   p += (size_t)MTOK * 4;
  float* nll  = (float*)p;
  float* psum = (float*)H1;  // H1 dead after GEMM2

  k_transpose_bf16<<<dim3(HID / 32, HID / 32), 256, 0, stream>>>(W1, W1t, HID, HID);
  k_transpose_bf16<<<dim3(HID / 32, HID / 32), 256, 0, stream>>>(W2, W2t, HID, HID);
  k_wo_frag<<<dim3(VOCAB / 128, HID / 64), 256, 0, stream>>>(Wo, WoQ);
  k_gather_e<<<MTOK, 256, 0, stream>>>(text, embed, E);

  k_gemm_ffn<0><<<dim3(HID / 128, MTOK / 128), 256, 0, stream>>>(E, W1t, b1, (void*)H1, HID);
  k_gemm_ffn<1><<<dim3(HID / 128, MTOK / 128), 256, 0, stream>>>(H1, W2t, b2, (void*)H2Q, HID);

  k_gemm_vocab_mx<<<dim3((MTOK / 128) * (VOCAB / 128)), 256, 0, stream>>>(
      H2Q, WoQ, bo, psum, tlog, target);

  k_reduce_nll<<<MTOK, 64, 0, stream>>>(psum, tlog, nll);
  k_loss<<<1, SS, 0, stream>>>(target, nll, out);
}